// Round 1
// baseline (409.589 us; speedup 1.0000x reference)
//
#include <hip/hip_runtime.h>
#include <math.h>

// Problem shape (fixed by reference)
#define B  32
#define C  512
#define HW 3136      // 56*56
#define HW4 784      // HW/4 float4 per channel
#define HID 32       // C/16
#define K  256       // C/2, top-k
#define BC (B * C)   // 16384 channels total

#define NBLK 2048    // G11: cap grid at ~2048 blocks, grid-stride the rest
#define NWAVE (NBLK * 4)

typedef float vfloat4 __attribute__((ext_vector_type(4)));

// ---------------------------------------------------------------------------
// Kernel 1: per-(b,c) mean+max pooling. ONE WAVE per channel, grid-strided.
// 2048 blocks x 4 independent waves; 2 channels per wave. No LDS, no
// __syncthreads — pure 64-lane shuffle reduction. x stays cache-resident
// (no nt) so scale_kernel can re-read it from LLC.
// ---------------------------------------------------------------------------
__global__ __launch_bounds__(256) void pool_kernel(const float* __restrict__ x,
                                                   float* __restrict__ y) {
    const int lane = threadIdx.x & 63;
    const int wgid = blockIdx.x * 4 + (threadIdx.x >> 6);
    for (int bc = wgid; bc < BC; bc += NWAVE) {
        const float4* xp = (const float4*)(x + (size_t)bc * HW);
        float sum = 0.f;
        float mx  = -INFINITY;
        // 784 float4 per channel, 64 lanes -> 12 full iters + 16-lane tail
        for (int i = lane; i < HW4; i += 64) {
            float4 v = xp[i];
            sum += (v.x + v.y) + (v.z + v.w);
            mx = fmaxf(mx, fmaxf(fmaxf(v.x, v.y), fmaxf(v.z, v.w)));
        }
        for (int off = 32; off > 0; off >>= 1) {
            sum += __shfl_down(sum, off, 64);
            mx   = fmaxf(mx, __shfl_down(mx, off, 64));
        }
        if (lane == 0)
            y[bc] = sum * (1.0f / (float)HW) + mx;
    }
}

// ---------------------------------------------------------------------------
// Kernel 2: per-batch-row MLP + sigmoid + kth-largest threshold + final map.
// One block (256 threads) per batch row; 32 blocks total. (unchanged)
// ---------------------------------------------------------------------------
__global__ __launch_bounds__(256) void mlp_kernel(const float* __restrict__ y,
                                                  const float* __restrict__ w1,
                                                  const float* __restrict__ b1,
                                                  const float* __restrict__ prelu_a,
                                                  const float* __restrict__ w2,
                                                  const float* __restrict__ b2,
                                                  const float* __restrict__ rnd,
                                                  float* __restrict__ fmap) {
    const int b = blockIdx.x;
    const int t = threadIdx.x;

    __shared__ __align__(16) float ylds[C];
    __shared__ float hlds[HID];
    __shared__ __align__(16) float y2[C];
    __shared__ float hpart[256];
    __shared__ float thresh;

    ylds[t]       = y[b * C + t];
    ylds[t + 256] = y[b * C + t + 256];
    __syncthreads();

    // h[j] = sum_c y[c] * w1[c][j] + b1[j], PReLU.
    // thread t owns (j = t&31, chunk = t>>5); 8 chunks of 64.
    {
        const int j = t & 31;
        const int chunk = t >> 5;
        float acc = 0.f;
        const int c0 = chunk * 64;
        #pragma unroll 8
        for (int c = c0; c < c0 + 64; ++c)
            acc += ylds[c] * w1[c * HID + j];
        hpart[t] = acc;
        __syncthreads();
        if (t < HID) {
            float a = ((hpart[t]       + hpart[t + 32]) + (hpart[t + 64]  + hpart[t + 96])) +
                      ((hpart[t + 128] + hpart[t + 160]) + (hpart[t + 192] + hpart[t + 224]));
            a += b1[t];
            const float al = prelu_a[0];
            hlds[t] = (a >= 0.f) ? a : al * a;
        }
    }
    __syncthreads();

    // y2[c] = sigmoid(h . w2[:,c] + b2[c]); thread t owns c = t and c = t+256
    {
        float acc0 = b2[t];
        float acc1 = b2[t + 256];
        #pragma unroll
        for (int j = 0; j < HID; ++j) {
            const float hj = hlds[j];
            acc0 += hj * w2[j * C + t];
            acc1 += hj * w2[j * C + t + 256];
        }
        y2[t]       = 1.f / (1.f + expf(-acc0));
        y2[t + 256] = 1.f / (1.f + expf(-acc1));
    }
    __syncthreads();

    // kth-largest via rank selection with index tie-break, both candidates in
    // one pass over y2 read as float4 LDS broadcasts (128 ds_read_b128).
    {
        const int cA = t, cB = t + 256;
        const float vA = y2[cA], vB = y2[cB];
        int rankA = 0, rankB = 0;
        const float4* y2v = (const float4*)y2;
        #pragma unroll 8
        for (int jj = 0; jj < C / 4; ++jj) {
            const float4 u = y2v[jj];
            const int j0 = jj * 4;
            rankA += (u.x > vA) || (u.x == vA && (j0    ) < cA);
            rankA += (u.y > vA) || (u.y == vA && (j0 + 1) < cA);
            rankA += (u.z > vA) || (u.z == vA && (j0 + 2) < cA);
            rankA += (u.w > vA) || (u.w == vA && (j0 + 3) < cA);
            rankB += (u.x > vB) || (u.x == vB && (j0    ) < cB);
            rankB += (u.y > vB) || (u.y == vB && (j0 + 1) < cB);
            rankB += (u.z > vB) || (u.z == vB && (j0 + 2) < cB);
            rankB += (u.w > vB) || (u.w == vB && (j0 + 3) < cB);
        }
        if (rankA == K - 1) thresh = vA;
        if (rankB == K - 1) thresh = vB;
    }
    __syncthreads();

    const float th = thresh;
    {
        const float vA = y2[t], vB = y2[t + 256];
        const float rbA = (rnd[b * C + t]       - 0.5f < 0.f) ? 1.f : 0.f;
        const float rbB = (rnd[b * C + t + 256] - 0.5f < 0.f) ? 1.f : 0.f;
        const float mkA = (vA - th < 0.f) ? 1.f : 0.f;
        const float mkB = (vB - th < 0.f) ? 1.f : 0.f;
        fmap[b * C + t]       = (rbA != 0.f) ? (mkA * vA) : vA;
        fmap[b * C + t + 256] = (rbB != 0.f) ? (mkB * vB) : vB;
    }
}

// ---------------------------------------------------------------------------
// Kernel 3: out = x * fmap[channel]. ONE WAVE per channel, grid-strided
// (2048 blocks x 4 waves; 2 channels per wave).
//  - fmap load: once per channel, wave-uniform -> scalarizable; the s==0
//    skip branch is wave-uniform (no divergence at channel boundaries).
//  - fmap==0 channels (~25%): skip the x load entirely, store zeros.
//  - nontemporal stores for out: keep x LLC-resident (x = 196 MiB < 256 MiB).
// ---------------------------------------------------------------------------
__global__ __launch_bounds__(256) void scale_kernel(const float* __restrict__ x,
                                                    const float* __restrict__ fmap,
                                                    float* __restrict__ out) {
    const int lane = threadIdx.x & 63;
    const int wgid = blockIdx.x * 4 + (threadIdx.x >> 6);
    for (int bc = wgid; bc < BC; bc += NWAVE) {
        const float s = fmap[bc];
        const size_t base = (size_t)bc * HW4;
        const vfloat4* xp  = (const vfloat4*)x + base;
        vfloat4*       op  = (vfloat4*)out + base;
        if (s == 0.f) {
            const vfloat4 z = (vfloat4)0.f;
            for (int i = lane; i < HW4; i += 64)
                __builtin_nontemporal_store(z, op + i);
        } else {
            for (int i = lane; i < HW4; i += 64) {
                vfloat4 v = xp[i];
                __builtin_nontemporal_store(v * s, op + i);
            }
        }
    }
}

extern "C" void kernel_launch(void* const* d_in, const int* in_sizes, int n_in,
                              void* d_out, int out_size, void* d_ws, size_t ws_size,
                              hipStream_t stream) {
    const float* x       = (const float*)d_in[0];
    const float* w1      = (const float*)d_in[1];
    const float* b1      = (const float*)d_in[2];
    const float* prelu_a = (const float*)d_in[3];
    const float* w2      = (const float*)d_in[4];
    const float* b2      = (const float*)d_in[5];
    const float* rnd     = (const float*)d_in[6];
    float* out = (float*)d_out;

    float* y    = (float*)d_ws;            // B*C floats
    float* fmap = y + B * C;               // B*C floats

    pool_kernel<<<NBLK, 256, 0, stream>>>(x, y);
    mlp_kernel<<<B, 256, 0, stream>>>(y, w1, b1, prelu_a, w2, b2, rnd, fmap);
    scale_kernel<<<NBLK, 256, 0, stream>>>(x, fmap, out);
}